// Round 2
// 155.014 us; speedup vs baseline: 1.0005x; 1.0005x over previous
//
#include <hip/hip_runtime.h>
#include <stdint.h>

#define BATCH 128
#define HH 14
#define WW 14
#define CC 512
#define HW (HH * WW)      // 196
#define KM_ITERS 10       // reference runs ITERS+1 = 11 assignment steps

// native clang vector type: accepted by __builtin_nontemporal_store,
// same layout/alignment as float4.
typedef float fx4 __attribute__((ext_vector_type(4)));

// ---------------------------------------------------------------------------
// Kernel 1 (fused): per-batch block.
//   Phase 1: thread c finds (arg1 = w of max, arg0 = h of max) with numpy's
//            first-index tie semantics for BOTH independent argmaxes.
//   Phase 2: wave 0 runs k-means (K=2, 11 steps) from LDS — arithmetic is
//            bit-identical to the previously-verified k_kmeans (all _rn
//            intrinsics, tie -> cluster 0, swapped centroid update).
//   Phase 3: block packs 512 assignment bytes into 128 uint32 mask words.
// This removes one kernel launch and the pts global round-trip entirely.
// ---------------------------------------------------------------------------
__global__ __launch_bounds__(512) void k_points_kmeans(const float* __restrict__ x,
                                                       uint32_t* __restrict__ am4) {
    const int b   = blockIdx.x;
    const int tid = threadIdx.x;

    __shared__ float2   s_pts[CC];          // 4 KiB
    __shared__ uint32_t s_assign4[CC / 4];  // 512 B, uint32-aligned byte store

    // ---- phase 1: max-pixel coordinates per channel -----------------------
    {
        const float* base = x + (size_t)b * HW * CC + tid;

        float colmax[WW];
#pragma unroll
        for (int w = 0; w < WW; ++w) colmax[w] = -INFINITY;

        float best = -INFINITY;
        int arg0 = 0;
        for (int h = 0; h < HH; ++h) {
            float rowmax = -INFINITY;
#pragma unroll
            for (int w = 0; w < WW; ++w) {
                float v = base[(size_t)(h * WW + w) * CC];
                rowmax = fmaxf(rowmax, v);
                colmax[w] = fmaxf(colmax[w], v);
            }
            if (rowmax > best) { best = rowmax; arg0 = h; }  // strict > keeps first h
        }
        int arg1 = -1;
#pragma unroll
        for (int w = 0; w < WW; ++w) {
            if (arg1 < 0 && colmax[w] == best) arg1 = w;      // first w attaining max
        }
        s_pts[tid] = make_float2((float)arg1, (float)arg0);
    }
    __syncthreads();

    // ---- phase 2: k-means on wave 0 (data from LDS, arithmetic unchanged) -
    if (tid < 64) {
        const int lane = tid;
        uint8_t* s_assign = (uint8_t*)s_assign4;

        float px[8], py[8];
#pragma unroll
        for (int j = 0; j < 8; ++j) {
            float2 p = s_pts[lane + 64 * j];
            px[j] = p.x; py[j] = p.y;
        }

        // totals over all 512 points (exact integers)
        float totx = 0.f, toty = 0.f;
#pragma unroll
        for (int j = 0; j < 8; ++j) { totx += px[j]; toty += py[j]; }
#pragma unroll
        for (int s = 32; s >= 1; s >>= 1) {
            totx += __shfl_xor(totx, s);
            toty += __shfl_xor(toty, s);
        }

        // initial centroids = points of channels 0 and 1
        float c0x = __shfl(px[0], 0), c0y = __shfl(py[0], 0);
        float c1x = __shfl(px[0], 1), c1y = __shfl(py[0], 1);

        int a[8];
        for (int it = 0; it <= KM_ITERS; ++it) {
            float sx = 0.f, sy = 0.f, cnt = 0.f;
#pragma unroll
            for (int j = 0; j < 8; ++j) {
                float dx0 = __fsub_rn(px[j], c0x);
                float dy0 = __fsub_rn(py[j], c0y);
                float d0  = __fadd_rn(__fmul_rn(dx0, dx0), __fmul_rn(dy0, dy0));
                float dx1 = __fsub_rn(px[j], c1x);
                float dy1 = __fsub_rn(py[j], c1y);
                float d1  = __fadd_rn(__fmul_rn(dx1, dx1), __fmul_rn(dy1, dy1));
                a[j] = (d1 < d0) ? 1 : 0;   // argmin: tie -> cluster 0
                if (a[j]) { sx += px[j]; sy += py[j]; cnt += 1.f; }
            }
#pragma unroll
            for (int s = 32; s >= 1; s >>= 1) {
                sx  += __shfl_xor(sx, s);
                sy  += __shfl_xor(sy, s);
                cnt += __shfl_xor(cnt, s);
            }
            float cnt0 = (float)CC - cnt;           // exact
            c0x = __fdiv_rn(sx, fmaxf(cnt, 1.f));   // note the swap: c0 from m1
            c0y = __fdiv_rn(sy, fmaxf(cnt, 1.f));
            c1x = __fdiv_rn(totx - sx, fmaxf(cnt0, 1.f));  // exact int subtraction
            c1y = __fdiv_rn(toty - sy, fmaxf(cnt0, 1.f));
        }

#pragma unroll
        for (int j = 0; j < 8; ++j)
            s_assign[lane + 64 * j] = (uint8_t)a[j];
    }
    __syncthreads();

    // ---- phase 3: pack 4 assignment bytes -> one uint32 mask word ---------
    if (tid < CC / 4) {
        am4[b * (CC / 4) + tid] = s_assign4[tid];
    }
}

// ---------------------------------------------------------------------------
// Kernel 2: scatter. One thread per float4 (4 channels). Mask loaded as one
// uint32 (4 assignment bytes). Writes C0 then C1 (concatenated in d_out).
// Output stores are non-temporal: outputs are never re-read, so keep the
// 102.8 MB write stream from evicting the input out of L2/L3 mid-kernel.
// ---------------------------------------------------------------------------
#define N4 (BATCH * HW * (CC / 4))   // 3,211,264 float4 per output

__global__ __launch_bounds__(256) void k_scatter(const fx4* __restrict__ x4,
                                                 const uint32_t* __restrict__ am4,
                                                 fx4* __restrict__ out4) {
    const int idx = blockIdx.x * 256 + threadIdx.x;
    if (idx >= N4) return;
    const int c4  = idx & (CC / 4 - 1);   // 0..127
    const int pix = idx >> 7;             // b*196 + hw
    const int b   = pix / HW;

    const uint32_t m = am4[b * (CC / 4) + c4];
    const fx4 v = x4[idx];

    fx4 o0, o1;
    o0.x = (m & 0x000000ffu) ? 0.f : v.x;  o1.x = (m & 0x000000ffu) ? v.x : 0.f;
    o0.y = (m & 0x0000ff00u) ? 0.f : v.y;  o1.y = (m & 0x0000ff00u) ? v.y : 0.f;
    o0.z = (m & 0x00ff0000u) ? 0.f : v.z;  o1.z = (m & 0x00ff0000u) ? v.z : 0.f;
    o0.w = (m & 0xff000000u) ? 0.f : v.w;  o1.w = (m & 0xff000000u) ? v.w : 0.f;

    __builtin_nontemporal_store(o0, &out4[idx]);        // C0
    __builtin_nontemporal_store(o1, &out4[idx + N4]);   // C1
}

// ---------------------------------------------------------------------------
extern "C" void kernel_launch(void* const* d_in, const int* in_sizes, int n_in,
                              void* d_out, int out_size, void* d_ws, size_t ws_size,
                              hipStream_t stream) {
    const float* x = (const float*)d_in[0];

    uint32_t* am4 = (uint32_t*)d_ws;   // 64 KiB of packed assignment masks

    k_points_kmeans<<<BATCH, 512, 0, stream>>>(x, am4);
    k_scatter<<<(N4 + 255) / 256, 256, 0, stream>>>(
        (const fx4*)x, am4, (fx4*)d_out);
}